// Round 10
// baseline (157.223 us; speedup 1.0000x reference)
//
#include <hip/hip_runtime.h>
#include <hip/hip_bf16.h>
#include <math.h>

#define NB 8
#define HH 64
#define WW 64
#define C 192
#define G 12
#define GC 16
#define P 9
#define NPIX (NB*HH*WW)

typedef __attribute__((ext_vector_type(8))) short short8;
typedef __attribute__((ext_vector_type(4))) float f32x4;
typedef unsigned short ushort;

__device__ __forceinline__ ushort to_bf16(float f) {
  __hip_bfloat16 b = __float2bfloat16(f);
  return *(ushort*)&b;
}
__device__ __forceinline__ float bf2f(ushort u) {
  union { unsigned u; float f; } cv; cv.u = ((unsigned)u) << 16; return cv.f;
}
__device__ __forceinline__ float bflo(unsigned u) {
  union { unsigned v; float f; } c; c.v = u << 16; return c.f;
}
__device__ __forceinline__ float bfhi(unsigned u) {
  union { unsigned v; float f; } c; c.v = u & 0xffff0000u; return c.f;
}

// ---------------- weight prep: transpose to [n][k] bf16 + fused bias ----------------
__global__ void prep_w_kernel(const float* __restrict__ in_w, const float* __restrict__ out_w,
    const float* __restrict__ off_w, const float* __restrict__ msk_w, const float* __restrict__ cfs_w,
    const float* __restrict__ off_b, const float* __restrict__ msk_b, const float* __restrict__ cfs_b,
    ushort* __restrict__ in_wt, ushort* __restrict__ out_wt, ushort* __restrict__ wf_t,
    float* __restrict__ bf_bias) {
  int idx = blockIdx.x*256 + threadIdx.x;
  if (idx < 36864) {
    int n = idx/192, k = idx%192;
    in_wt[idx] = to_bf16(in_w[k*192 + n]);
  } else if (idx < 73728) {
    int j = idx - 36864; int n = j/192, k = j%192;
    out_wt[j] = to_bf16(out_w[k*192 + n]);
  } else if (idx < 147456) {
    int j = idx - 73728; int n = j/192, k = j%192;
    float v = 0.f;
    if (n < 216)      v = off_w[k*216 + n];
    else if (n < 324) v = msk_w[k*108 + (n-216)];
    else if (n < 336) v = cfs_w[k*12  + (n-324)];
    wf_t[j] = to_bf16(v);
  }
  if (idx < 384) {
    float b = 0.f;
    if (idx < 216)      b = off_b[idx];
    else if (idx < 324) b = msk_b[idx-216];
    else if (idx < 336) b = cfs_b[idx-324];
    bf_bias[idx] = b;
  }
}

// ---------------- bf16 MFMA GEMM (optional bf16 out; optional f32 A converted in-reg) ----
template<int NW, int NSTORE, bool BF16OUT, bool AF32>
__global__ __launch_bounds__(256) void mfma_gemm(const void* __restrict__ A_,
    const ushort* __restrict__ Wt, const float* __restrict__ bias,
    void* __restrict__ Cout_) {
  __shared__ ushort As[4*128*8];
  __shared__ ushort Bs[4*64*8];
  int pix0 = blockIdx.x * 128, n0 = blockIdx.y * 64;
  int tid = threadIdx.x;
  int wid = tid >> 6, lane = tid & 63;
  int lr = lane >> 4, lc = lane & 15;

  f32x4 acc[2][4];
  #pragma unroll
  for (int m=0;m<2;m++)
    #pragma unroll
    for (int j=0;j<4;j++) acc[m][j] = (f32x4){0.f,0.f,0.f,0.f};

  int sa0_kb = tid >> 7,        sa0_row = tid & 127;
  int sa1_kb = (tid+256) >> 7,  sa1_row = (tid+256) & 127;
  int sb_kb  = tid >> 6,        sb_n    = tid & 63;

  short8 pa0, pa1, pb;
  auto load_tile = [&](int k0) {
    if (AF32) {
      const float* Af = (const float*)A_;
      float4 u0 = *(const float4*)&Af[(size_t)(pix0 + sa0_row)*192 + k0 + sa0_kb*8];
      float4 u1 = *(const float4*)&Af[(size_t)(pix0 + sa0_row)*192 + k0 + sa0_kb*8 + 4];
      pa0[0]=to_bf16(u0.x); pa0[1]=to_bf16(u0.y); pa0[2]=to_bf16(u0.z); pa0[3]=to_bf16(u0.w);
      pa0[4]=to_bf16(u1.x); pa0[5]=to_bf16(u1.y); pa0[6]=to_bf16(u1.z); pa0[7]=to_bf16(u1.w);
      float4 v0 = *(const float4*)&Af[(size_t)(pix0 + sa1_row)*192 + k0 + sa1_kb*8];
      float4 v1 = *(const float4*)&Af[(size_t)(pix0 + sa1_row)*192 + k0 + sa1_kb*8 + 4];
      pa1[0]=to_bf16(v0.x); pa1[1]=to_bf16(v0.y); pa1[2]=to_bf16(v0.z); pa1[3]=to_bf16(v0.w);
      pa1[4]=to_bf16(v1.x); pa1[5]=to_bf16(v1.y); pa1[6]=to_bf16(v1.z); pa1[7]=to_bf16(v1.w);
    } else {
      const ushort* Ab = (const ushort*)A_;
      pa0 = *(const short8*)&Ab[(size_t)(pix0 + sa0_row)*192 + k0 + sa0_kb*8];
      pa1 = *(const short8*)&Ab[(size_t)(pix0 + sa1_row)*192 + k0 + sa1_kb*8];
    }
    pb  = *(const short8*)&Wt[(size_t)(n0 + sb_n)*192 + k0 + sb_kb*8];
  };
  load_tile(0);

  for (int t = 0; t < 6; t++) {
    __syncthreads();
    *(short8*)&As[(size_t)tid*8]        = pa0;
    *(short8*)&As[(size_t)(tid+256)*8]  = pa1;
    *(short8*)&Bs[(size_t)tid*8]        = pb;
    __syncthreads();
    if (t < 5) load_tile((t+1)*32);
    short8 a0 = *(const short8*)&As[(size_t)(lr*128 + wid*32 + lc)*8];
    short8 a1 = *(const short8*)&As[(size_t)(lr*128 + wid*32 + 16 + lc)*8];
    #pragma unroll
    for (int j=0;j<4;j++) {
      short8 b = *(const short8*)&Bs[(size_t)(lr*64 + j*16 + lc)*8];
      acc[0][j] = __builtin_amdgcn_mfma_f32_16x16x32_bf16(a0, b, acc[0][j], 0,0,0);
      acc[1][j] = __builtin_amdgcn_mfma_f32_16x16x32_bf16(a1, b, acc[1][j], 0,0,0);
    }
  }
  #pragma unroll
  for (int j=0;j<4;j++) {
    int col = n0 + j*16 + lc;
    if (NW != NSTORE && col >= NSTORE) continue;
    float bb = bias[col];
    #pragma unroll
    for (int m=0;m<2;m++) {
      size_t rbase = pix0 + wid*32 + m*16 + lr*4;
      #pragma unroll
      for (int r=0;r<4;r++) {
        float v = acc[m][j][r] + bb;
        if (BF16OUT) ((ushort*)Cout_)[(rbase + r)*NSTORE + col] = to_bf16(v);
        else         ((float*) Cout_)[(rbase + r)*NSTORE + col] = v;
      }
    }
  }
}

// ------- depthwise 5x5 + LN + GELU, sliding-window: block = 16-pixel row segment -------
#define SEG 16
__global__ __launch_bounds__(192) void dw_ln_gelu_kernel(const float* __restrict__ x,
    const float* __restrict__ dw_w, const float* __restrict__ dw_b,
    const float* __restrict__ ln_g, const float* __restrict__ ln_b,
    ushort* __restrict__ u_out) {
  int blk = blockIdx.x;                // ((n*HH + h)*4 + qw)
  int qw = blk & 3; int nh = blk >> 2;
  int h = nh & 63, n = nh >> 6;
  int c = threadIdx.x;
  int w0 = qw * SEG;

  float kw[25];
  #pragma unroll
  for (int t=0;t<25;t++) kw[t] = dw_w[t*C + c];

  float acc[SEG];
  float bb = dw_b[c];
  #pragma unroll
  for (int i=0;i<SEG;i++) acc[i] = bb;

  #pragma unroll
  for (int i=0;i<5;i++) {
    int hy = h + i - 2;
    if (hy < 0 || hy >= HH) continue;
    const float* rowp = &x[(((size_t)n*HH + hy)*WW)*C + c];
    #pragma unroll
    for (int wi=0; wi<SEG+4; wi++) {
      int w_in = w0 - 2 + wi;
      if (w_in < 0 || w_in >= WW) continue;
      float v = rowp[(size_t)w_in*C];
      #pragma unroll
      for (int j=0;j<5;j++) {
        int a = wi - j;
        if (a >= 0 && a < SEG) acc[a] += v * kw[i*5+j];
      }
    }
  }

  __shared__ float lds_acc[SEG][C+1];
  __shared__ float part1[SEG][12], part2[SEG][12];
  __shared__ float mu_s[SEG], rs_s[SEG];
  #pragma unroll
  for (int i=0;i<SEG;i++) lds_acc[i][c] = acc[i];
  __syncthreads();
  {
    int p = threadIdx.x & 15, chunk = threadIdx.x >> 4;
    float s1 = 0.f, s2 = 0.f;
    #pragma unroll
    for (int k=0;k<16;k++) {
      float v = lds_acc[p][chunk*16 + k];
      s1 += v; s2 += v*v;
    }
    part1[p][chunk] = s1; part2[p][chunk] = s2;
  }
  __syncthreads();
  if (threadIdx.x < SEG) {
    int p = threadIdx.x;
    float t1 = 0.f, t2 = 0.f;
    #pragma unroll
    for (int k=0;k<12;k++){ t1 += part1[p][k]; t2 += part2[p][k]; }
    float mu = t1 * (1.0f/C);
    float var = t2 * (1.0f/C) - mu*mu;
    mu_s[p] = mu; rs_s[p] = rsqrtf(var + 1e-5f);
  }
  __syncthreads();
  float gg = ln_g[c], lb = ln_b[c];
  size_t obase = ((size_t)nh*WW + w0)*C + c;
  #pragma unroll
  for (int i=0;i<SEG;i++) {
    float uv = (acc[i] - mu_s[i])*rs_s[i]*gg + lb;
    uv = 0.5f*uv*(1.0f + erff(uv*0.70710678118654752f));
    u_out[obase + (size_t)i*C] = to_bf16(uv);
  }
}

// ---------------- DCNv3 sampling + gated blend: 8x8 px tile, LDS-staged window ----------
// Window = 12x12 cells in padded coords [h0-1, h0+10]x[w0-1, w0+10], zero-extended
// (zero-extension == reference's zeros padding, so fast path needs NO validity masks).
// Cell padded to 400B (100 dwords = 4 banks) to break 384%128==0 conflicts.
#define CELLB 400
__device__ __forceinline__ void fma16(float* acc, float wv, uint4 q0, uint4 q1) {
  acc[0] += wv*bflo(q0.x); acc[1] += wv*bfhi(q0.x);
  acc[2] += wv*bflo(q0.y); acc[3] += wv*bfhi(q0.y);
  acc[4] += wv*bflo(q0.z); acc[5] += wv*bfhi(q0.z);
  acc[6] += wv*bflo(q0.w); acc[7] += wv*bfhi(q0.w);
  acc[8]  += wv*bflo(q1.x); acc[9]  += wv*bfhi(q1.x);
  acc[10] += wv*bflo(q1.y); acc[11] += wv*bfhi(q1.y);
  acc[12] += wv*bflo(q1.z); acc[13] += wv*bfhi(q1.z);
  acc[14] += wv*bflo(q1.w); acc[15] += wv*bfhi(q1.w);
}
__global__ __launch_bounds__(256) void sample_kernel(const ushort* __restrict__ omc,
    const ushort* __restrict__ x_proj, ushort* __restrict__ y_out) {
  __shared__ uint4 xs4[144*CELLB/16];          // 57.6 KB
  char* xs = (char*)xs4;
  int blk = blockIdx.x;
  int n = blk >> 6, ty = (blk >> 3) & 7, tx = blk & 7;
  int h0 = ty*8, w0 = tx*8;
  int tid = threadIdx.x;

  // stage window: cell (r,c) <- unpadded (h0+r-2, w0+c-2), zero if OOB
  for (int i = tid; i < 144*24; i += 256) {
    int cell = i / 24, k = i - cell*24;
    int r = cell / 12, c = cell - r*12;
    int y_u = h0 + r - 2, x_u = w0 + c - 2;
    uint4 v = {0u,0u,0u,0u};
    if ((unsigned)y_u < 64u && (unsigned)x_u < 64u)
      v = *(const uint4*)&x_proj[((size_t)n*4096 + y_u*64 + x_u)*192 + k*8];
    *(uint4*)&xs[cell*CELLB + k*16] = v;
  }
  __syncthreads();

  int px = tid >> 2, qq = tid & 3;
  int py = px >> 3, pxx = px & 7;
  int h = h0 + py, w = w0 + pxx;
  size_t pix = (size_t)n*4096 + h*64 + w;
  const unsigned* omc32 = (const unsigned*)omc;
  const char* xb = (const char*)x_proj;
  int mycell = (py+2)*12 + (pxx+2);            // own px: padded y=h+1 -> r=py+2
  const float pts[3] = {-1.f, 0.f, 1.f};

  for (int j = 0; j < 3; j++) {
    int g = qq*3 + j;
    int gch = g*32;                            // byte offset of group's 16ch in a cell
    // per-(px,g) softmax + sigmoid, all in registers
    float lv[9];
    #pragma unroll
    for (int p=0;p<9;p++) lv[p] = bf2f(omc[pix*336 + 216 + g*9 + p]);
    float mx = lv[0];
    #pragma unroll
    for (int p=1;p<9;p++) mx = fmaxf(mx, lv[p]);
    float msum = 0.f;
    #pragma unroll
    for (int p=0;p<9;p++){ lv[p] = expf(lv[p]-mx); msum += lv[p]; }
    float cf = 1.0f/(1.0f+expf(-bf2f(omc[pix*336 + 324 + g])));
    float onemcf = (1.0f - cf) / msum;
    float acc[16];
    #pragma unroll
    for (int k2=0;k2<16;k2++) acc[k2] = 0.f;

    #pragma unroll
    for (int p=0;p<9;p++) {
      unsigned off2 = omc32[pix*168 + g*9 + p];
      float ox = bflo(off2), oy = bfhi(off2);
      float gx = 1.0f + (float)w + pts[p/3] + ox;
      float gy = 1.0f + (float)h + pts[p%3] + oy;
      float x0f = floorf(gx), y0f = floorf(gy);
      float wx1 = gx-x0f, wy1 = gy-y0f;
      float wx0 = 1.f-wx1, wy0 = 1.f-wy1;
      int x0 = (int)x0f, y0 = (int)y0f;
      int c0 = x0 - (w0-1), r0 = y0 - (h0-1);
      float m = lv[p]*onemcf;
      float w00 = wx0*wy0*m, w01 = wx1*wy0*m, w10 = wx0*wy1*m, w11 = wx1*wy1*m;
      if ((unsigned)c0 <= 10u && (unsigned)r0 <= 10u) {
        int b = (r0*12 + c0)*CELLB + gch;
        uint4 qa0 = *(const uint4*)&xs[b],             qa1 = *(const uint4*)&xs[b+16];
        uint4 qb0 = *(const uint4*)&xs[b+CELLB],       qb1 = *(const uint4*)&xs[b+CELLB+16];
        uint4 qc0 = *(const uint4*)&xs[b+12*CELLB],    qc1 = *(const uint4*)&xs[b+12*CELLB+16];
        uint4 qd0 = *(const uint4*)&xs[b+13*CELLB],    qd1 = *(const uint4*)&xs[b+13*CELLB+16];
        fma16(acc, w00, qa0, qa1);
        fma16(acc, w01, qb0, qb1);
        fma16(acc, w10, qc0, qc1);
        fma16(acc, w11, qd0, qd1);
      } else {                                  // rare fallback: global gather w/ masks
        bool xv0 = (x0>=1)&&(x0<=64), xv1 = (x0>=0)&&(x0<=63);
        bool yv0 = (y0>=1)&&(y0<=64), yv1 = (y0>=0)&&(y0<=63);
        int base = n*4096;
        size_t ea = (yv0&&xv0) ? (size_t)(base + (y0-1)*64 + (x0-1))*384 : 0;
        size_t eb = (yv0&&xv1) ? (size_t)(base + (y0-1)*64 + (x0  ))*384 : 0;
        size_t ec = (yv1&&xv0) ? (size_t)(base + (y0  )*64 + (x0-1))*384 : 0;
        size_t ed = (yv1&&xv1) ? (size_t)(base + (y0  )*64 + (x0  ))*384 : 0;
        float wa = (yv0&&xv0)?w00:0.f, wb2 = (yv0&&xv1)?w01:0.f;
        float wc = (yv1&&xv0)?w10:0.f, wd2 = (yv1&&xv1)?w11:0.f;
        uint4 qa0 = *(const uint4*)(xb + ea + gch), qa1 = *(const uint4*)(xb + ea + gch + 16);
        uint4 qb0 = *(const uint4*)(xb + eb + gch), qb1 = *(const uint4*)(xb + eb + gch + 16);
        uint4 qc0 = *(const uint4*)(xb + ec + gch), qc1 = *(const uint4*)(xb + ec + gch + 16);
        uint4 qd0 = *(const uint4*)(xb + ed + gch), qd1 = *(const uint4*)(xb + ed + gch + 16);
        fma16(acc, wa, qa0, qa1);
        fma16(acc, wb2, qb0, qb1);
        fma16(acc, wc, qc0, qc1);
        fma16(acc, wd2, qd0, qd1);
      }
    }
    { // + cf * own pixel (from LDS window)
      int b = mycell*CELLB + gch;
      uint4 q0 = *(const uint4*)&xs[b], q1 = *(const uint4*)&xs[b+16];
      fma16(acc, cf, q0, q1);
    }
    short8 r0v, r1v;
    #pragma unroll
    for (int k2=0;k2<8;k2++){ r0v[k2] = to_bf16(acc[k2]); r1v[k2] = to_bf16(acc[8+k2]); }
    *(short8*)&y_out[pix*192 + g*16] = r0v;
    *(short8*)&y_out[pix*192 + g*16 + 8] = r1v;
  }
}

// ---------------- patch attention, LDS-tiled 8x8 px/block ----------------
__global__ __launch_bounds__(256) void pattn_kernel(const float* __restrict__ x,
    const ushort* __restrict__ x1, float* __restrict__ out) {
  __shared__ unsigned xs[100*97];      // 38800 B
  __shared__ float psc[64][36];        // 9216 B
  __shared__ float sd_s[64];
  int blk = blockIdx.x;
  int n = blk >> 6;
  int ty = (blk >> 3) & 7, tx = blk & 7;
  int th0 = ty*8, tw0 = tx*8;
  int tid = threadIdx.x;
  const unsigned* x1u = (const unsigned*)x1;
  for (int i = tid; i < 100*96; i += 256) {
    int cell = i / 96, wd = i - cell*96;
    int gy = th0 - 1 + cell/10, gx = tw0 - 1 + cell%10;
    unsigned v = 0;
    if (gy>=0 && gy<HH && gx>=0 && gx<WW)
      v = x1u[(((size_t)n*HH+gy)*WW+gx)*96 + wd];
    xs[cell*97 + wd] = v;
  }
  __syncthreads();
  {
    int px = tid >> 2, qq = tid & 3;
    int py = px >> 3, pxx = px & 7;
    int cell = (py+1)*10 + (pxx+1);
    float cen[48];
    #pragma unroll
    for (int k=0;k<24;k++) {
      unsigned w = xs[cell*97 + qq*24 + k];
      cen[2*k] = bflo(w); cen[2*k+1] = bfhi(w);
    }
    #pragma unroll
    for (int ni=0;ni<9;ni++) {
      int nc = cell + (ni/3-1)*10 + (ni%3-1);
      float a = 0.f;
      #pragma unroll
      for (int k=0;k<24;k++) {
        unsigned w = xs[nc*97 + qq*24 + k];
        a += cen[2*k]*bflo(w) + cen[2*k+1]*bfhi(w);
      }
      psc[px][qq*9+ni] = a;
    }
  }
  __syncthreads();
  if (tid < 64) {
    float sc[9];
    #pragma unroll
    for (int k=0;k<9;k++)
      sc[k] = psc[tid][k] + psc[tid][9+k] + psc[tid][18+k] + psc[tid][27+k];
    float m = sc[0];
    #pragma unroll
    for (int k=1;k<9;k++) m = fmaxf(m, sc[k]);
    float pr[9]; float s = 0.f;
    #pragma unroll
    for (int k=0;k<9;k++){ pr[k] = expf(sc[k]-m); s += pr[k]; }
    float inv = 1.0f/s;
    float mean = 0.f;
    #pragma unroll
    for (int k=0;k<9;k++){ pr[k] *= inv; mean += pr[k]; }
    mean *= (1.0f/9.0f);
    float var = 0.f;
    #pragma unroll
    for (int k=0;k<9;k++){ float d = pr[k]-mean; var += d*d; }
    sd_s[tid] = sqrtf(var*(1.0f/8.0f));
  }
  __syncthreads();
  for (int i = tid; i < 64*96; i += 256) {
    int p2 = i / 96, wd = i - p2*96;
    int py2 = p2 >> 3, px2 = p2 & 7;
    unsigned v = xs[((py2+1)*10 + (px2+1))*97 + wd];
    size_t pix = ((size_t)n*HH + th0+py2)*WW + tw0+px2;
    float2 xv = ((const float2*)x)[pix*96 + wd];
    float sd = sd_s[p2];
    float2 o; o.x = xv.x + bflo(v)*sd; o.y = xv.y + bfhi(v)*sd;
    ((float2*)out)[pix*96 + wd] = o;
  }
}

extern "C" void kernel_launch(void* const* d_in, const int* in_sizes, int n_in,
                              void* d_out, int out_size, void* d_ws, size_t ws_size,
                              hipStream_t stream) {
  const float* x     = (const float*)d_in[0];
  const float* dw_w  = (const float*)d_in[1];
  const float* dw_b  = (const float*)d_in[2];
  const float* ln_g  = (const float*)d_in[3];
  const float* ln_b  = (const float*)d_in[4];
  const float* off_w = (const float*)d_in[5];
  const float* off_b = (const float*)d_in[6];
  const float* msk_w = (const float*)d_in[7];
  const float* msk_b = (const float*)d_in[8];
  const float* in_w  = (const float*)d_in[9];
  const float* in_b  = (const float*)d_in[10];
  const float* out_w = (const float*)d_in[11];
  const float* out_b = (const float*)d_in[12];
  const float* cfs_w = (const float*)d_in[13];
  const float* cfs_b = (const float*)d_in[14];
  float* outp = (float*)d_out;

  ushort* omc    = (ushort*)d_ws;                        // NPIX*336 bf16
  ushort* xproj  = omc + (size_t)NPIX*336;               // NPIX*192 bf16
  ushort* x1_bf  = xproj + (size_t)NPIX*192;             // NPIX*192 bf16 (x1)
  ushort* u_bf   = x1_bf + (size_t)NPIX*192;             // NPIX*192 bf16 (u, then y2)
  ushort* in_wt  = u_bf + (size_t)NPIX*192;              // 192*192
  ushort* out_wt = in_wt + 192*192;                      // 192*192
  ushort* wf_t   = out_wt + 192*192;                     // 384*192
  float*  bfb    = (float*)(wf_t + 384*192);             // 384 f32

  prep_w_kernel<<<(147456+255)/256, 256, 0, stream>>>(in_w, out_w, off_w, msk_w, cfs_w,
                                                       off_b, msk_b, cfs_b,
                                                       in_wt, out_wt, wf_t, bfb);
  // x_proj (bf16) = x @ in_w + in_b  (f32 A converted in-register)
  mfma_gemm<192,192,true,true><<<dim3(NPIX/128, 3), 256, 0, stream>>>(x, in_wt, in_b, xproj);
  // u (bf16) = GELU(LN(dwconv(x)))
  dw_ln_gelu_kernel<<<NB*HH*4, 192, 0, stream>>>(x, dw_w, dw_b, ln_g, ln_b, u_bf);
  // omc (bf16) = u @ wf + bf
  mfma_gemm<384,336,true,false><<<dim3(NPIX/128, 6), 256, 0, stream>>>(u_bf, wf_t, bfb, omc);
  // y2 (bf16) = dcn-sample + gated blend (overwrites u)
  sample_kernel<<<NB*64, 256, 0, stream>>>(omc, xproj, u_bf);
  // x1 (bf16) = y2 @ out_w + out_b
  mfma_gemm<192,192,true,false><<<dim3(NPIX/128, 3), 256, 0, stream>>>(u_bf, out_wt, out_b, x1_bf);
  // out = x + x1 * patch_std
  pattn_kernel<<<NB*64, 256, 0, stream>>>(x, x1_bf, outp);
}